// Round 5
// baseline (519.383 us; speedup 1.0000x reference)
//
#include <hip/hip_runtime.h>
#include <hip/hip_cooperative_groups.h>

namespace cg = cooperative_groups;

#define B 4
#define TQ 256
#define TK 1024
#define QS 512
#define NN 128

// exp(2y) = exp2(y * 2*log2(e)); projections are pre-scaled by this in P1.
#define TANH_SCALE 2.8853900817779268f
#define LOG2E 1.4426950408889634f
#define CTX_ELEMS ((size_t)B * TQ * QS)

__device__ __forceinline__ float fast_exp2(float x) {
#if __has_builtin(__builtin_amdgcn_exp2f)
    return __builtin_amdgcn_exp2f(x);
#else
    return exp2f(x);
#endif
}
__device__ __forceinline__ float fast_rcp(float x) {
#if __has_builtin(__builtin_amdgcn_rcpf)
    return __builtin_amdgcn_rcpf(x);
#else
    return 1.0f / x;
#endif
}

union SmemU {
    struct { float As[32][18]; float Bs[32][132]; } p1;   // 19200 B
    struct { float aqs[2][128]; float vsm[128]; float red[2][8]; } p2;
    struct { float Wst[32][34]; float Ks[32][64]; } p3;   // 12544 B
};

// ---------------------------------------------------------------------------
// Single cooperative kernel, 512 blocks x 256 threads (2 blocks/CU).
// P1: projections (320 blocks active). P2: scores+softmax (512 q-pairs).
// P3: context split-K=2 partials (512 units). P4: reduce partials.
// ---------------------------------------------------------------------------
__global__ __launch_bounds__(256, 2) void fused_kernel(
    const float* __restrict__ query, const float* __restrict__ keys,
    const float* __restrict__ Wq, const float* __restrict__ Wk,
    const float* __restrict__ vatt,
    float* __restrict__ attq, float* __restrict__ attkT,
    float* __restrict__ ctxp, float* __restrict__ ctx,
    float* __restrict__ wout)
{
    __shared__ SmemU sm;
    cg::grid_group grid = cg::this_grid();
    const int tid = threadIdx.x;
    const int bid = blockIdx.x;

    // ================= P1: projections =================
    if (bid < 320) {
        const int rb = bid * 16;
        const bool isq = (rb < B * TQ);
        const float* A = isq ? (query + (size_t)rb * QS)
                             : (keys + (size_t)(rb - B * TQ) * QS);
        const float* W = isq ? Wq : Wk;

        const int n0 = (tid & 31) * 4;
        const int q0 = (tid >> 5) * 2;
        float acc[2][4] = {};

        for (int k0 = 0; k0 < QS; k0 += 32) {
            {
                const int r = tid >> 4, c = tid & 15;
                const float2 v = *(const float2*)(A + (size_t)r * QS + k0 + c * 2);
                sm.p1.As[c * 2 + 0][r] = v.x;
                sm.p1.As[c * 2 + 1][r] = v.y;
            }
            {
                const int n = (tid & 31) * 4, r0 = tid >> 5;
                #pragma unroll
                for (int j = 0; j < 4; ++j) {
                    const int kk = r0 + j * 8;
                    *(float4*)&sm.p1.Bs[kk][n] =
                        *(const float4*)(W + (size_t)(k0 + kk) * NN + n);
                }
            }
            __syncthreads();
            #pragma unroll
            for (int kk = 0; kk < 32; ++kk) {
                const float2 a = *(const float2*)&sm.p1.As[kk][q0];
                const float4 b = *(const float4*)&sm.p1.Bs[kk][n0];
                acc[0][0] = fmaf(a.x, b.x, acc[0][0]);
                acc[0][1] = fmaf(a.x, b.y, acc[0][1]);
                acc[0][2] = fmaf(a.x, b.z, acc[0][2]);
                acc[0][3] = fmaf(a.x, b.w, acc[0][3]);
                acc[1][0] = fmaf(a.y, b.x, acc[1][0]);
                acc[1][1] = fmaf(a.y, b.y, acc[1][1]);
                acc[1][2] = fmaf(a.y, b.z, acc[1][2]);
                acc[1][3] = fmaf(a.y, b.w, acc[1][3]);
            }
            __syncthreads();
        }

        if (isq) {
            float* out = attq + (size_t)rb * NN;
            #pragma unroll
            for (int i = 0; i < 2; ++i) {
                float4 o;
                o.x = acc[i][0] * TANH_SCALE;
                o.y = acc[i][1] * TANH_SCALE;
                o.z = acc[i][2] * TANH_SCALE;
                o.w = acc[i][3] * TANH_SCALE;
                *(float4*)(out + (size_t)(q0 + i) * NN + n0) = o;
            }
        } else {
            #pragma unroll
            for (int i = 0; i < 2; ++i) {
                float4 o;
                o.x = acc[i][0] * TANH_SCALE;
                o.y = acc[i][1] * TANH_SCALE;
                o.z = acc[i][2] * TANH_SCALE;
                o.w = acc[i][3] * TANH_SCALE;
                *(float4*)&sm.p1.Bs[q0 + i][n0] = o;
            }
            __syncthreads();
            const int rk = rb - B * TQ;
            const int bb = rk >> 10;
            const int kbase = rk & 1023;
            const int n = tid >> 1;
            const int kh = (tid & 1) * 8;
            float* o = attkT + (size_t)bb * NN * TK + (size_t)n * TK + kbase + kh;
            #pragma unroll
            for (int m4 = 0; m4 < 2; ++m4) {
                float4 t;
                t.x = sm.p1.Bs[kh + m4 * 4 + 0][n];
                t.y = sm.p1.Bs[kh + m4 * 4 + 1][n];
                t.z = sm.p1.Bs[kh + m4 * 4 + 2][n];
                t.w = sm.p1.Bs[kh + m4 * 4 + 3][n];
                *(float4*)(o + m4 * 4) = t;
            }
        }
    }
    __threadfence();
    grid.sync();

    // ================= P2: scores + softmax =================
    {
        const int b = bid >> 7;
        const int q0 = (bid & 127) * 2;

        if (tid < 128) {
            sm.p2.aqs[0][tid] = attq[((size_t)b * TQ + q0) * NN + tid];
            sm.p2.vsm[tid] = vatt[tid];
        } else {
            sm.p2.aqs[1][tid & 127] =
                attq[((size_t)b * TQ + q0 + 1) * NN + (tid & 127)];
        }
        __syncthreads();

        const float* kt = attkT + (size_t)b * NN * TK + (size_t)tid * 4;
        float s[2][4] = {};

        #pragma unroll 8
        for (int n = 0; n < 128; ++n) {
            const float4 a = *(const float4*)(kt + (size_t)n * TK);
            const float a0 = sm.p2.aqs[0][n], a1 = sm.p2.aqs[1][n];
            const float vv = sm.p2.vsm[n];
            const float av[4] = {a.x, a.y, a.z, a.w};
            #pragma unroll
            for (int r = 0; r < 4; ++r) {
                const float x0 = a0 + av[r];
                const float t0 = fmaf(-2.f, fast_rcp(1.f + fast_exp2(x0)), 1.f);
                s[0][r] = fmaf(vv, t0, s[0][r]);
                const float x1 = a1 + av[r];
                const float t1 = fmaf(-2.f, fast_rcp(1.f + fast_exp2(x1)), 1.f);
                s[1][r] = fmaf(vv, t1, s[1][r]);
            }
        }

        const int lane = tid & 63, wid = tid >> 6;
        #pragma unroll
        for (int qq = 0; qq < 2; ++qq) {
            float mm = fmaxf(fmaxf(s[qq][0], s[qq][1]), fmaxf(s[qq][2], s[qq][3]));
            #pragma unroll
            for (int off = 32; off > 0; off >>= 1)
                mm = fmaxf(mm, __shfl_xor(mm, off, 64));
            if (lane == 0) sm.p2.red[qq][wid] = mm;
        }
        __syncthreads();
        float m[2];
        m[0] = fmaxf(fmaxf(sm.p2.red[0][0], sm.p2.red[0][1]),
                     fmaxf(sm.p2.red[0][2], sm.p2.red[0][3]));
        m[1] = fmaxf(fmaxf(sm.p2.red[1][0], sm.p2.red[1][1]),
                     fmaxf(sm.p2.red[1][2], sm.p2.red[1][3]));

        float e[2][4];
        #pragma unroll
        for (int qq = 0; qq < 2; ++qq) {
            float ls = 0.f;
            #pragma unroll
            for (int i = 0; i < 4; ++i) {
                e[qq][i] = fast_exp2((s[qq][i] - m[qq]) * LOG2E);
                ls += e[qq][i];
            }
            #pragma unroll
            for (int off = 32; off > 0; off >>= 1)
                ls += __shfl_xor(ls, off, 64);
            if (lane == 0) sm.p2.red[qq][4 + wid] = ls;
        }
        __syncthreads();
        #pragma unroll
        for (int qq = 0; qq < 2; ++qq) {
            const float S = sm.p2.red[qq][4] + sm.p2.red[qq][5] +
                            sm.p2.red[qq][6] + sm.p2.red[qq][7];
            const float inv = fast_rcp(S);
            float4 w4;
            w4.x = e[qq][0] * inv; w4.y = e[qq][1] * inv;
            w4.z = e[qq][2] * inv; w4.w = e[qq][3] * inv;
            *(float4*)(wout + ((size_t)b * TQ + q0 + qq) * TK + (size_t)tid * 4) = w4;
        }
    }
    __threadfence();
    grid.sync();

    // ================= P3: context partials, split-K=2 =================
    {
        const int b = bid >> 7;
        const int rem = bid & 127;
        const int qt = rem >> 4;        // 8 q-tiles of 32
        const int dt = (rem >> 1) & 7;  // 8 d-tiles of 64
        const int ks = rem & 1;         // k half

        const float* wb = wout + (size_t)b * TQ * TK + (size_t)qt * 32 * TK + ks * 512;
        const float* kb = keys + (size_t)b * TK * QS + (size_t)ks * 512 * QS + dt * 64;

        const int d0 = (tid & 15) * 4;
        const int q0 = (tid >> 4) * 2;
        float acc[2][4] = {};

        for (int k0 = 0; k0 < 512; k0 += 32) {
            {
                const int r = tid >> 3, c = tid & 7;
                const float4 v = *(const float4*)(wb + (size_t)r * TK + k0 + c * 4);
                sm.p3.Wst[c * 4 + 0][r] = v.x;
                sm.p3.Wst[c * 4 + 1][r] = v.y;
                sm.p3.Wst[c * 4 + 2][r] = v.z;
                sm.p3.Wst[c * 4 + 3][r] = v.w;
            }
            {
                const int c = tid & 15, r = tid >> 4;
                *(float4*)&sm.p3.Ks[r][c * 4] =
                    *(const float4*)(kb + (size_t)(k0 + r) * QS + c * 4);
                *(float4*)&sm.p3.Ks[r + 16][c * 4] =
                    *(const float4*)(kb + (size_t)(k0 + r + 16) * QS + c * 4);
            }
            __syncthreads();
            #pragma unroll
            for (int kk = 0; kk < 32; ++kk) {
                const float2 a = *(const float2*)&sm.p3.Wst[kk][q0];
                const float4 bb = *(const float4*)&sm.p3.Ks[kk][d0];
                acc[0][0] = fmaf(a.x, bb.x, acc[0][0]);
                acc[0][1] = fmaf(a.x, bb.y, acc[0][1]);
                acc[0][2] = fmaf(a.x, bb.z, acc[0][2]);
                acc[0][3] = fmaf(a.x, bb.w, acc[0][3]);
                acc[1][0] = fmaf(a.y, bb.x, acc[1][0]);
                acc[1][1] = fmaf(a.y, bb.y, acc[1][1]);
                acc[1][2] = fmaf(a.y, bb.z, acc[1][2]);
                acc[1][3] = fmaf(a.y, bb.w, acc[1][3]);
            }
            __syncthreads();
        }

        float* op = ctxp + (size_t)ks * CTX_ELEMS
                  + ((size_t)b * TQ + qt * 32 + q0) * QS + dt * 64 + d0;
        #pragma unroll
        for (int i = 0; i < 2; ++i) {
            float4 o;
            o.x = acc[i][0]; o.y = acc[i][1]; o.z = acc[i][2]; o.w = acc[i][3];
            *(float4*)(op + (size_t)i * QS) = o;
        }
    }
    __threadfence();
    grid.sync();

    // ================= P4: reduce the 2 partials =================
    {
        const size_t idx = (size_t)bid * 256 + tid;   // 512*256 = 131072 float4
        const size_t stride = CTX_ELEMS / 4;
        const float4* p = (const float4*)ctxp;
        const float4 a = p[idx];
        const float4 b4 = p[idx + stride];
        float4 o;
        o.x = a.x + b4.x;
        o.y = a.y + b4.y;
        o.z = a.z + b4.z;
        o.w = a.w + b4.w;
        ((float4*)ctx)[idx] = o;
    }
}

// ---------------------------------------------------------------------------
extern "C" void kernel_launch(void* const* d_in, const int* in_sizes, int n_in,
                              void* d_out, int out_size, void* d_ws, size_t ws_size,
                              hipStream_t stream) {
    const float* query = (const float*)d_in[0];  // (4,256,512)
    const float* keys  = (const float*)d_in[1];  // (4,1024,512)
    const float* Wq    = (const float*)d_in[2];  // (512,128)
    const float* Wk    = (const float*)d_in[3];  // (512,128)
    const float* vatt  = (const float*)d_in[4];  // (128,)

    float* ctx = (float*)d_out;                       // 4*256*512
    float* wts = ctx + CTX_ELEMS;                     // 4*256*1024

    float* attq  = (float*)d_ws;                      // 4*256*128
    float* attkT = attq + (size_t)B * TQ * NN;        // 4*128*1024 (transposed)
    float* ctxp  = attkT + (size_t)B * NN * TK;       // 2 * CTX_ELEMS partials

    void* args[] = {
        (void*)&query, (void*)&keys, (void*)&Wq, (void*)&Wk, (void*)&vatt,
        (void*)&attq, (void*)&attkT, (void*)&ctxp, (void*)&ctx, (void*)&wts,
    };
    hipLaunchCooperativeKernel((const void*)fused_kernel, dim3(512), dim3(256),
                               args, 0, stream);
}

// Round 6
// 156.114 us; speedup vs baseline: 3.3269x; 3.3269x over previous
//
#include <hip/hip_runtime.h>

#define B 4
#define TQ 256
#define TK 1024
#define QS 512
#define NN 128
#define QPB 4   // q-rows per block in the fused kernel

// exp(2y) = exp2(y * 2*log2(e)); projections are pre-scaled by this in K1.
#define TANH_SCALE 2.8853900817779268f
#define LOG2E 1.4426950408889634f
#define CTX_ELEMS ((size_t)B * TQ * QS)

__device__ __forceinline__ float fast_exp2(float x) {
#if __has_builtin(__builtin_amdgcn_exp2f)
    return __builtin_amdgcn_exp2f(x);
#else
    return exp2f(x);
#endif
}
__device__ __forceinline__ float fast_rcp(float x) {
#if __has_builtin(__builtin_amdgcn_rcpf)
    return __builtin_amdgcn_rcpf(x);
#else
    return 1.0f / x;
#endif
}

// ---------------------------------------------------------------------------
// K1: fused projections (unchanged from R4). Row space = [1024 q ; 4096 k].
// Block: 16 rows x 128 cols, BK=32, 256 threads, 2x4 microtile. 320 blocks.
// Query rows -> attq[q][n] (scaled). Keys rows -> attkT[b][n][k] (scaled).
// ---------------------------------------------------------------------------
__global__ __launch_bounds__(256) void proj_kernel(
    const float* __restrict__ query, const float* __restrict__ keys,
    const float* __restrict__ Wq, const float* __restrict__ Wk,
    float* __restrict__ attq, float* __restrict__ attkT)
{
    __shared__ float As[32][18];
    __shared__ float Bs[32][132];

    const int tid = threadIdx.x;
    const int rb = blockIdx.x * 16;
    const bool isq = (rb < B * TQ);
    const float* A = isq ? (query + (size_t)rb * QS)
                         : (keys + (size_t)(rb - B * TQ) * QS);
    const float* W = isq ? Wq : Wk;

    const int n0 = (tid & 31) * 4;
    const int q0 = (tid >> 5) * 2;
    float acc[2][4] = {};

    for (int k0 = 0; k0 < QS; k0 += 32) {
        {
            const int r = tid >> 4, c = tid & 15;
            const float2 v = *(const float2*)(A + (size_t)r * QS + k0 + c * 2);
            As[c * 2 + 0][r] = v.x;
            As[c * 2 + 1][r] = v.y;
        }
        {
            const int n = (tid & 31) * 4, r0 = tid >> 5;
            #pragma unroll
            for (int j = 0; j < 4; ++j) {
                const int kk = r0 + j * 8;
                *(float4*)&Bs[kk][n] =
                    *(const float4*)(W + (size_t)(k0 + kk) * NN + n);
            }
        }
        __syncthreads();
        #pragma unroll
        for (int kk = 0; kk < 32; ++kk) {
            const float2 a = *(const float2*)&As[kk][q0];
            const float4 b = *(const float4*)&Bs[kk][n0];
            acc[0][0] = fmaf(a.x, b.x, acc[0][0]);
            acc[0][1] = fmaf(a.x, b.y, acc[0][1]);
            acc[0][2] = fmaf(a.x, b.z, acc[0][2]);
            acc[0][3] = fmaf(a.x, b.w, acc[0][3]);
            acc[1][0] = fmaf(a.y, b.x, acc[1][0]);
            acc[1][1] = fmaf(a.y, b.y, acc[1][1]);
            acc[1][2] = fmaf(a.y, b.z, acc[1][2]);
            acc[1][3] = fmaf(a.y, b.w, acc[1][3]);
        }
        __syncthreads();
    }

    if (isq) {
        float* out = attq + (size_t)rb * NN;
        #pragma unroll
        for (int i = 0; i < 2; ++i) {
            float4 o;
            o.x = acc[i][0] * TANH_SCALE;
            o.y = acc[i][1] * TANH_SCALE;
            o.z = acc[i][2] * TANH_SCALE;
            o.w = acc[i][3] * TANH_SCALE;
            *(float4*)(out + (size_t)(q0 + i) * NN + n0) = o;
        }
    } else {
        #pragma unroll
        for (int i = 0; i < 2; ++i) {
            float4 o;
            o.x = acc[i][0] * TANH_SCALE;
            o.y = acc[i][1] * TANH_SCALE;
            o.z = acc[i][2] * TANH_SCALE;
            o.w = acc[i][3] * TANH_SCALE;
            *(float4*)&Bs[q0 + i][n0] = o;
        }
        __syncthreads();
        const int rk = rb - B * TQ;
        const int bb = rk >> 10;
        const int kbase = rk & 1023;
        const int n = tid >> 1;
        const int kh = (tid & 1) * 8;
        float* o = attkT + (size_t)bb * NN * TK + (size_t)n * TK + kbase + kh;
        #pragma unroll
        for (int m4 = 0; m4 < 2; ++m4) {
            float4 t;
            t.x = Bs[kh + m4 * 4 + 0][n];
            t.y = Bs[kh + m4 * 4 + 1][n];
            t.z = Bs[kh + m4 * 4 + 2][n];
            t.w = Bs[kh + m4 * 4 + 3][n];
            *(float4*)(o + m4 * 4) = t;
        }
    }
}

// ---------------------------------------------------------------------------
// K2: fused scores + softmax + context. 256 blocks x 512 threads.
// Block owns (batch b, 4 q-rows) -> softmax->context dependency is block-local.
// XCD swizzle: bid&7 -> XCD; b = (bid&7)>>1 so each XCD's L2 caches ONE
// batch's keys (2 MB fits the 4 MB per-XCD L2).
// Scores: lane owns 2 contiguous k's (coalesced attkT reads, 8B/lane).
// Context: k split across 4 thread-groups, w from LDS (wave-uniform b128
// broadcast reads), keys float4 coalesced; LDS tree-reduce across groups.
// ---------------------------------------------------------------------------
__global__ __launch_bounds__(512) void score_ctx_kernel(
    const float* __restrict__ attq, const float* __restrict__ attkT,
    const float* __restrict__ vatt, const float* __restrict__ keys,
    float* __restrict__ wout, float* __restrict__ ctx)
{
    __shared__ float aqs[QPB][NN];       // 2 KB
    __shared__ float vsm[NN];            // 0.5 KB
    __shared__ float red[QPB][8];
    __shared__ float wls[QPB][TK];       // 16 KB softmaxed weights
    __shared__ float rbuf[4][QPB][QS];   // 32 KB split-k partials

    const int tid = threadIdx.x;
    const int bid = blockIdx.x;
    const int xcd = bid & 7;
    const int b = xcd >> 1;                       // batch pinned to XCD pair
    const int qg = ((bid >> 3) << 1) | (xcd & 1); // 0..63
    const int q0 = qg * QPB;

    if (tid < NN) vsm[tid] = vatt[tid];
    if (tid < QPB * NN) {
        const int qq = tid >> 7, nn = tid & 127;
        aqs[qq][nn] = attq[((size_t)b * TQ + q0 + qq) * NN + nn];
    }
    __syncthreads();

    // ---- scores: lane owns k2 = tid*2, tid*2+1 ----
    const int k2 = tid * 2;
    const float* kt = attkT + (size_t)b * NN * TK + k2;
    float s[QPB][2] = {};

    #pragma unroll 4
    for (int n = 0; n < NN; ++n) {
        const float2 a = *(const float2*)(kt + (size_t)n * TK);
        const float vv = vsm[n];
        #pragma unroll
        for (int q = 0; q < QPB; ++q) {
            const float aq = aqs[q][n];
            const float x0 = aq + a.x;
            const float t0 = fmaf(-2.f, fast_rcp(1.f + fast_exp2(x0)), 1.f);
            s[q][0] = fmaf(vv, t0, s[q][0]);
            const float x1 = aq + a.y;
            const float t1 = fmaf(-2.f, fast_rcp(1.f + fast_exp2(x1)), 1.f);
            s[q][1] = fmaf(vv, t1, s[q][1]);
        }
    }

    // ---- softmax over 1024 k (2 per thread) for each of 4 q ----
    const int lane = tid & 63, wv = tid >> 6;   // 8 waves
    #pragma unroll
    for (int q = 0; q < QPB; ++q) {
        float mm = fmaxf(s[q][0], s[q][1]);
        #pragma unroll
        for (int off = 32; off > 0; off >>= 1)
            mm = fmaxf(mm, __shfl_xor(mm, off, 64));
        if (lane == 0) red[q][wv] = mm;
    }
    __syncthreads();
    float m[QPB];
    #pragma unroll
    for (int q = 0; q < QPB; ++q) {
        float mm = red[q][0];
        #pragma unroll
        for (int j = 1; j < 8; ++j) mm = fmaxf(mm, red[q][j]);
        m[q] = mm;
    }
    __syncthreads();

    float e[QPB][2];
    #pragma unroll
    for (int q = 0; q < QPB; ++q) {
        e[q][0] = fast_exp2((s[q][0] - m[q]) * LOG2E);
        e[q][1] = fast_exp2((s[q][1] - m[q]) * LOG2E);
        float ls = e[q][0] + e[q][1];
        #pragma unroll
        for (int off = 32; off > 0; off >>= 1)
            ls += __shfl_xor(ls, off, 64);
        if (lane == 0) red[q][wv] = ls;
    }
    __syncthreads();
    #pragma unroll
    for (int q = 0; q < QPB; ++q) {
        float S = red[q][0];
        #pragma unroll
        for (int j = 1; j < 8; ++j) S += red[q][j];
        const float inv = fast_rcp(S);
        float2 w2;
        w2.x = e[q][0] * inv;
        w2.y = e[q][1] * inv;
        *(float2*)(wout + ((size_t)b * TQ + q0 + q) * TK + k2) = w2;
        *(float2*)&wls[q][k2] = w2;
    }
    __syncthreads();

    // ---- context: ctx[q][d] = sum_k w[q][k] * keys[b][k][d], k-split x4 ----
    const int g = tid >> 7;           // k-group 0..3 (256 k's each)
    const int d0 = (tid & 127) * 4;   // 128 threads cover d=0..511
    const float* kbp = keys + (size_t)b * TK * QS + d0;
    float acc[QPB][4] = {};

    const int kbeg = g * 256;
    for (int k = kbeg; k < kbeg + 256; k += 4) {
        float4 kv[4];
        #pragma unroll
        for (int i = 0; i < 4; ++i)
            kv[i] = *(const float4*)(kbp + (size_t)(k + i) * QS);
        #pragma unroll
        for (int q = 0; q < QPB; ++q) {
            const float4 wq = *(const float4*)&wls[q][k];  // wave-uniform bcast
            acc[q][0] = fmaf(wq.x, kv[0].x, acc[q][0]);
            acc[q][1] = fmaf(wq.x, kv[0].y, acc[q][1]);
            acc[q][2] = fmaf(wq.x, kv[0].z, acc[q][2]);
            acc[q][3] = fmaf(wq.x, kv[0].w, acc[q][3]);
            acc[q][0] = fmaf(wq.y, kv[1].x, acc[q][0]);
            acc[q][1] = fmaf(wq.y, kv[1].y, acc[q][1]);
            acc[q][2] = fmaf(wq.y, kv[1].z, acc[q][2]);
            acc[q][3] = fmaf(wq.y, kv[1].w, acc[q][3]);
            acc[q][0] = fmaf(wq.z, kv[2].x, acc[q][0]);
            acc[q][1] = fmaf(wq.z, kv[2].y, acc[q][1]);
            acc[q][2] = fmaf(wq.z, kv[2].z, acc[q][2]);
            acc[q][3] = fmaf(wq.z, kv[2].w, acc[q][3]);
            acc[q][0] = fmaf(wq.w, kv[3].x, acc[q][0]);
            acc[q][1] = fmaf(wq.w, kv[3].y, acc[q][1]);
            acc[q][2] = fmaf(wq.w, kv[3].z, acc[q][2]);
            acc[q][3] = fmaf(wq.w, kv[3].w, acc[q][3]);
        }
    }

    // stage all 4 groups' partials, then thread (g,d0) finalizes q=g
    #pragma unroll
    for (int q = 0; q < QPB; ++q)
        *(float4*)&rbuf[g][q][d0] = *(float4*)&acc[q][0];
    __syncthreads();

    {
        const int q = g;   // this thread finalizes row q0+g, cols d0..d0+3
        float4 o = *(const float4*)&rbuf[0][q][d0];
        #pragma unroll
        for (int gg = 1; gg < 4; ++gg) {
            const float4 p = *(const float4*)&rbuf[gg][q][d0];
            o.x += p.x; o.y += p.y; o.z += p.z; o.w += p.w;
        }
        *(float4*)(ctx + ((size_t)b * TQ + q0 + q) * QS + d0) = o;
    }
}

// ---------------------------------------------------------------------------
extern "C" void kernel_launch(void* const* d_in, const int* in_sizes, int n_in,
                              void* d_out, int out_size, void* d_ws, size_t ws_size,
                              hipStream_t stream) {
    const float* query = (const float*)d_in[0];  // (4,256,512)
    const float* keys  = (const float*)d_in[1];  // (4,1024,512)
    const float* Wq    = (const float*)d_in[2];  // (512,128)
    const float* Wk    = (const float*)d_in[3];  // (512,128)
    const float* vatt  = (const float*)d_in[4];  // (128,)

    float* ctx = (float*)d_out;                  // 4*256*512
    float* wts = ctx + CTX_ELEMS;                // 4*256*1024

    float* attq  = (float*)d_ws;                 // 4*256*128
    float* attkT = attq + (size_t)B * TQ * NN;   // 4*128*1024 (transposed)

    hipLaunchKernelGGL(proj_kernel, dim3((B * TQ + B * TK) / 16), dim3(256), 0,
                       stream, query, keys, Wq, Wk, attq, attkT);
    hipLaunchKernelGGL(score_ctx_kernel, dim3(B * TQ / QPB), dim3(512), 0,
                       stream, attq, attkT, vatt, keys, wts, ctx);
}